// Round 9
// baseline (755.262 us; speedup 1.0000x reference)
//
#include <hip/hip_runtime.h>
#include <hip/hip_bf16.h>

#define NS 65536
#define NQ 131072
#define DD 256
#define NC 1024
#define BM 32
#define LCAP 128
#define NTILES 8
#define NBLK (NQ / BM / NTILES)   // 512 persistent blocks

typedef __attribute__((ext_vector_type(8))) short short8;
typedef __attribute__((ext_vector_type(4))) float f32x4;

// LDS carve (bytes): B ring 4 x 16384 at 0; A [32][512] at 65536. Total 80 KB
// -> 2 blocks/CU. After A-hoist the A region is overlaid with qinv(+0),
// redM(+1024), redS(+2048). After each tile's K-loop the B ring is overlaid
// with a [16][1024] f32 output image (two passes), then re-staged next tile.
#define SMEM_B     0
#define SMEM_A     65536
#define SMEM_TOTAL 81920

static __device__ __forceinline__ unsigned short f2bf(float f) {
    unsigned int u = __float_as_uint(f);
    u += 0x7fffu + ((u >> 16) & 1u);          // round-to-nearest-even
    return (unsigned short)(u >> 16);
}

static __device__ __forceinline__ void gload_lds16(const void* src, void* dst) {
    using GPtr = const __attribute__((address_space(1))) unsigned int*;
    using LPtr = __attribute__((address_space(3))) unsigned int*;
    GPtr g = reinterpret_cast<GPtr>(reinterpret_cast<uintptr_t>(src));
    LPtr l = reinterpret_cast<LPtr>(static_cast<unsigned int>(reinterpret_cast<uintptr_t>(dst)));
    __builtin_amdgcn_global_load_lds(g, l, 16, 0, 0);
}

// K1: one sf pass: per-row rinv (wave per row) + per-class compact row list.
__global__ __launch_bounds__(256) void k_count(const float* __restrict__ sf,
                                               const int* __restrict__ labels,
                                               float* __restrict__ rinv,
                                               int* __restrict__ cnts,
                                               int* __restrict__ lists) {
    const int row  = (blockIdx.x << 2) + (threadIdx.x >> 6);
    const int lane = threadIdx.x & 63;
    float4 v = *reinterpret_cast<const float4*>(sf + (size_t)row * DD + lane * 4);
    float ss = v.x*v.x + v.y*v.y + v.z*v.z + v.w*v.w;
#pragma unroll
    for (int off = 32; off; off >>= 1) ss += __shfl_xor(ss, off);
    if (lane == 0) {
        rinv[row] = 1.0f / fmaxf(sqrtf(ss), 1e-8f);
        const int lab = labels[row];
        const int slot = atomicAdd(&cnts[lab], 1);
        if (slot < LCAP) lists[lab * LCAP + slot] = row;
    }
}

// K2: block per class, gather listed rows, mean -> l2norm -> bf16 + arange tail.
__global__ __launch_bounds__(256) void k_proto(const float* __restrict__ sf,
                                               const float* __restrict__ rinv,
                                               const int* __restrict__ cnts,
                                               const int* __restrict__ lists,
                                               unsigned short* __restrict__ pb,
                                               float* __restrict__ outTail) {
    __shared__ float red[4];
    const int c = blockIdx.x;
    const int t = threadIdx.x;
    const int total = cnts[c];
    const int n = min(total, LCAP);
    float acc = 0.f;
    for (int j = 0; j < n; ++j) {
        const int row = lists[c * LCAP + j];
        acc += sf[(size_t)row * DD + t] * rinv[row];
    }
    const float m = acc / fmaxf((float)total, 1.0f);
    float ss = m * m;
#pragma unroll
    for (int off = 32; off; off >>= 1) ss += __shfl_xor(ss, off);
    if ((t & 63) == 0) red[t >> 6] = ss;
    __syncthreads();
    const float tot = red[0] + red[1] + red[2] + red[3];
    const float r = 1.0f / fmaxf(sqrtf(tot), 1e-8f);
    pb[(size_t)c * DD + t] = f2bf(m * r);
    if (t == 0) outTail[c] = (float)c;
}

// K3: persistent fused GEMM + qnorm + log_softmax. 512 blocks x 8 tiles,
// 512 thr = 8 waves (qg=w>>2, cq=w&3), BM=32, 2 blocks/CU.
// Per-block unit ROTATION (krot dims, crot classes) de-hotspots L2: concurrent
// blocks read different 16-KB B slices at any instant. Rotation lives only in
// ADDRESSES (stage src, A-hoist src, image slot); all register indices stay
// compile-time. Ring-4, stage-after-barrier, counted vmcnt (R8-proven).
__global__ __launch_bounds__(512, 4) void k_gemm_lsm(const float* __restrict__ qf,
                                                     const unsigned short* __restrict__ pb,
                                                     float* __restrict__ out) {
    extern __shared__ char smem[];
    const int tid  = threadIdx.x;
    const int w    = tid >> 6;
    const int lane = tid & 63;
    const int g    = lane >> 4;
    const int r16  = lane & 15;
    const int qg   = w >> 2;
    const int cq   = w & 3;
    const int krot = blockIdx.x & 7;
    const int crot = (blockIdx.x >> 3) & 3;
    const char* pbB = (const char*)pb;

    // stage unit u into ring slot u&3. Physical unit: dims kkp*32, classes
    // cup*256. LDS [256 c][64 B] linear dest; source pre-swizzled (s ^ (c&3)).
#define STAGE(u)                                                                         \
    {                                                                                    \
        const int kkp_ = (((u) >> 2) + krot) & 7;                                        \
        const int cup_ = (((u) & 3) + crot) & 3;                                         \
        char* dst_ = smem + SMEM_B + ((u) & 3) * 16384 + w * 2048;                       \
        const char* gbase_ = pbB + ((size_t)(cup_ * 256) << 9) + (kkp_ << 6);            \
        _Pragma("unroll")                                                                \
        for (int i = 0; i < 2; ++i) {                                                    \
            const int e = w * 128 + i * 64 + lane;                                       \
            const int c = e >> 2, s = e & 3;                                             \
            const char* src = gbase_ + ((size_t)c << 9) + ((s ^ (c & 3)) << 4);          \
            gload_lds16(src, dst_ + i * 1024);                                           \
        }                                                                                \
    }

#pragma unroll 1
    for (int tile = 0; tile < NTILES; ++tile) {
        const size_t qbase = ((size_t)blockIdx.x * NTILES + tile) * BM;

        // ---- prologue: issue units 0..2, A-stage; one full drain ----
        STAGE(0);
        STAGE(1);
        STAGE(2);
        float rinvLocal = 0.f;
        {
            const int row = tid >> 4;            // 0..31
            const int seg = tid & 15;            // 16 dims (64 B) each
            const float* qrow = qf + (qbase + row) * (size_t)DD + seg * 16;
            float4 f0 = *reinterpret_cast<const float4*>(qrow + 0);
            float4 f1 = *reinterpret_cast<const float4*>(qrow + 4);
            float4 f2 = *reinterpret_cast<const float4*>(qrow + 8);
            float4 f3 = *reinterpret_cast<const float4*>(qrow + 12);
            float ss = f0.x*f0.x + f0.y*f0.y + f0.z*f0.z + f0.w*f0.w
                     + f1.x*f1.x + f1.y*f1.y + f1.z*f1.z + f1.w*f1.w
                     + f2.x*f2.x + f2.y*f2.y + f2.z*f2.z + f2.w*f2.w
                     + f3.x*f3.x + f3.y*f3.y + f3.z*f3.z + f3.w*f3.w;
            ss += __shfl_xor(ss, 1); ss += __shfl_xor(ss, 2);
            ss += __shfl_xor(ss, 4); ss += __shfl_xor(ss, 8);
            rinvLocal = 1.0f / fmaxf(sqrtf(ss), 1e-8f);
            short8 h0, h1;
            h0[0]=(short)f2bf(f0.x); h0[1]=(short)f2bf(f0.y); h0[2]=(short)f2bf(f0.z); h0[3]=(short)f2bf(f0.w);
            h0[4]=(short)f2bf(f1.x); h0[5]=(short)f2bf(f1.y); h0[6]=(short)f2bf(f1.z); h0[7]=(short)f2bf(f1.w);
            h1[0]=(short)f2bf(f2.x); h1[1]=(short)f2bf(f2.y); h1[2]=(short)f2bf(f2.z); h1[3]=(short)f2bf(f2.w);
            h1[4]=(short)f2bf(f3.x); h1[5]=(short)f2bf(f3.y); h1[6]=(short)f2bf(f3.z); h1[7]=(short)f2bf(f3.w);
            const int x = row & 7;
            char* aRow = smem + SMEM_A + row * 512;
            *reinterpret_cast<short8*>(aRow + (((seg*2)     ^ x) << 4)) = h0;
            *reinterpret_cast<short8*>(aRow + (((seg*2 + 1) ^ x) << 4)) = h1;
        }
        __syncthreads();   // drains: units 0-2 + A + prev-tile stores (L2-ack)

        // hoist query frags with dim ROTATION baked in: a[kk] holds dims
        // ((kk+krot)&7)*32 .. so the K-loop can index a[u>>2] compile-time.
        short8 a[8];
        {
            const int arow = qg * 16 + r16;
#pragma unroll
            for (int kk = 0; kk < 8; ++kk) {
                const int kkp = (kk + krot) & 7;
                const int chunk = (kkp * 4 + g) ^ (arow & 7);
                a[kk] = *reinterpret_cast<const short8*>(smem + SMEM_A + arow * 512 + chunk * 16);
            }
        }
        __syncthreads();   // all waves hoisted; A region free for overlays

        if ((lane & 15) == 0)
            reinterpret_cast<float*>(smem + SMEM_A)[tid >> 4] = rinvLocal;

        f32x4 acc[16];
#pragma unroll
        for (int n = 0; n < 16; ++n) acc[n] = (f32x4){0.f, 0.f, 0.f, 0.f};

        // ---- main loop: 32 units, ring-4, stage-after-barrier, counted vmcnt ----
#pragma unroll
        for (int u = 0; u < 32; ++u) {
            if (u <= 29)      { asm volatile("s_waitcnt vmcnt(4)" ::: "memory"); }
            else if (u == 30) { asm volatile("s_waitcnt vmcnt(2)" ::: "memory"); }
            else              { asm volatile("s_waitcnt vmcnt(0)" ::: "memory"); }
            asm volatile("s_barrier" ::: "memory");
            if (u + 3 < 32) STAGE(u + 3);
            const char* base = smem + SMEM_B + (u & 3) * 16384;
            __builtin_amdgcn_s_setprio(1);
#pragma unroll
            for (int np = 0; np < 4; ++np) {
                const int cl = np * 64 + cq * 16 + r16;          // local class in unit
                short8 b = *reinterpret_cast<const short8*>(base + cl * 64 + ((g ^ (cl & 3)) << 4));
                acc[(u & 3) * 4 + np] = __builtin_amdgcn_mfma_f32_16x16x32_bf16(b, a[u >> 2], acc[(u & 3) * 4 + np], 0, 0, 0);
            }
            __builtin_amdgcn_s_setprio(0);
        }
        __syncthreads();   // K done (vmcnt=0 from u=31); B ring becomes image

        // ---- epilogue: qinv scale + row log_softmax ----
        float* qinvLds = reinterpret_cast<float*>(smem + SMEM_A);
        float* redM = reinterpret_cast<float*>(smem + SMEM_A + 1024);   // [32][4]
        float* redS = reinterpret_cast<float*>(smem + SMEM_A + 2048);   // [32][4]
        const int myrow = qg * 16 + r16;
        const float qi = qinvLds[myrow];

#pragma unroll
        for (int n = 0; n < 16; ++n)
#pragma unroll
            for (int j = 0; j < 4; ++j) acc[n][j] *= qi;

        float m = acc[0][0];
#pragma unroll
        for (int n = 0; n < 16; ++n)
#pragma unroll
            for (int j = 0; j < 4; ++j) m = fmaxf(m, acc[n][j]);
        m = fmaxf(m, __shfl_xor(m, 16));
        m = fmaxf(m, __shfl_xor(m, 32));
        if (lane < 16) redM[myrow * 4 + cq] = m;
        __syncthreads();
        float rowM = redM[myrow * 4 + 0];
#pragma unroll
        for (int k = 1; k < 4; ++k) rowM = fmaxf(rowM, redM[myrow * 4 + k]);

        float s = 0.f;
#pragma unroll
        for (int n = 0; n < 16; ++n)
#pragma unroll
            for (int j = 0; j < 4; ++j) s += __expf(acc[n][j] - rowM);
        s += __shfl_xor(s, 16);
        s += __shfl_xor(s, 32);
        if (lane < 16) redS[myrow * 4 + cq] = s;
        __syncthreads();
        float rs = redS[myrow * 4 + 0];
#pragma unroll
        for (int k = 1; k < 4; ++k) rs += redS[myrow * 4 + k];
        const float lse = rowM + __logf(rs);

        // ---- stores via [16][1024] f32 image in dead B ring, 2 passes.
        // Raw barriers only (no vmcnt drain) so stores stay fire-and-forget
        // and HBM-drain under the NEXT tile's K-loop. Class slot uses the
        // ROTATED physical class (runtime address math, compile-time regs).
#pragma unroll
        for (int pass = 0; pass < 2; ++pass) {
            if (qg == pass) {
#pragma unroll
                for (int n = 0; n < 16; ++n) {
                    f32x4 v;
#pragma unroll
                    for (int j = 0; j < 4; ++j) v[j] = acc[n][j] - lse;
                    const int cup = ((n >> 2) + crot) & 3;
                    const int slot = cup * 64 + (n & 3) * 16 + cq * 4 + g;   // 16B slot
                    *reinterpret_cast<f32x4*>(smem + r16 * 4096 + ((slot ^ (r16 & 7)) << 4)) = v;
                }
            }
            asm volatile("s_waitcnt lgkmcnt(0)" ::: "memory");
            asm volatile("s_barrier" ::: "memory");
            {
                const int row = tid >> 5;        // 0..15
                const int s0  = tid & 31;
                float* gout = out + (qbase + pass * 16 + row) * (size_t)NC;
#pragma unroll
                for (int p = 0; p < 8; ++p) {
                    const int slot = p * 32 + s0;
                    f32x4 v = *reinterpret_cast<const f32x4*>(smem + row * 4096 + ((slot ^ (row & 7)) << 4));
                    *reinterpret_cast<f32x4*>(gout + slot * 4) = v;
                }
            }
            asm volatile("s_barrier" ::: "memory");   // readers done -> next pass / next tile
        }
    }
}

extern "C" void kernel_launch(void* const* d_in, const int* in_sizes, int n_in,
                              void* d_out, int out_size, void* d_ws, size_t ws_size,
                              hipStream_t stream) {
    const float* sf     = (const float*)d_in[0];
    const int*   labels = (const int*)d_in[1];
    const float* qf     = (const float*)d_in[2];
    float* out = (float*)d_out;

    char* ws = (char*)d_ws;
    float* rinv         = (float*)ws;                          // 256 KiB
    unsigned short* pb  = (unsigned short*)(ws + 262144);      // 512 KiB
    int* cnts           = (int*)(ws + 786432);                 // 4 KiB
    int* lists          = (int*)(ws + 790528);                 // 512 KiB

    hipFuncSetAttribute(reinterpret_cast<const void*>(k_gemm_lsm),
                        hipFuncAttributeMaxDynamicSharedMemorySize, SMEM_TOTAL);

    hipMemsetAsync(cnts, 0, NC * sizeof(int), stream);

    k_count<<<NS / 4, 256, 0, stream>>>(sf, labels, rinv, cnts, lists);

    float* outTail = out + (size_t)out_size - NC;
    k_proto<<<NC, 256, 0, stream>>>(sf, rinv, cnts, lists, pb, outTail);

    k_gemm_lsm<<<NBLK, 512, SMEM_TOTAL, stream>>>(qf, pb, out);
}

// Round 10
// 719.046 us; speedup vs baseline: 1.0504x; 1.0504x over previous
//
#include <hip/hip_runtime.h>
#include <hip/hip_bf16.h>

#define NS 65536
#define NQ 131072
#define DD 256
#define NC 1024
#define BM 32
#define LCAP 128
#define NTILES 8
#define NBLK (NQ / BM / NTILES)   // 512 persistent blocks = 2/CU

typedef __attribute__((ext_vector_type(8))) short short8;
typedef __attribute__((ext_vector_type(4))) float f32x4;

// LDS carve (bytes): B ring 4 x 16384 at 0; A [32][512] at 65536. Total 80 KB
// -> 2 blocks/CU. After A-hoist the A region is overlaid with qinv(+0),
// redM(+1024), redS(+2048). After each tile's K-loop the B ring is overlaid
// with a [16][1024] f32 output image (two passes), then re-staged next tile.
#define SMEM_B     0
#define SMEM_A     65536
#define SMEM_TOTAL 81920

static __device__ __forceinline__ unsigned short f2bf(float f) {
    unsigned int u = __float_as_uint(f);
    u += 0x7fffu + ((u >> 16) & 1u);          // round-to-nearest-even
    return (unsigned short)(u >> 16);
}

static __device__ __forceinline__ void gload_lds16(const void* src, void* dst) {
    using GPtr = const __attribute__((address_space(1))) unsigned int*;
    using LPtr = __attribute__((address_space(3))) unsigned int*;
    GPtr g = reinterpret_cast<GPtr>(reinterpret_cast<uintptr_t>(src));
    LPtr l = reinterpret_cast<LPtr>(static_cast<unsigned int>(reinterpret_cast<uintptr_t>(dst)));
    __builtin_amdgcn_global_load_lds(g, l, 16, 0, 0);
}

// K1: one sf pass: per-row rinv (wave per row) + per-class compact row list.
__global__ __launch_bounds__(256) void k_count(const float* __restrict__ sf,
                                               const int* __restrict__ labels,
                                               float* __restrict__ rinv,
                                               int* __restrict__ cnts,
                                               int* __restrict__ lists) {
    const int row  = (blockIdx.x << 2) + (threadIdx.x >> 6);
    const int lane = threadIdx.x & 63;
    float4 v = *reinterpret_cast<const float4*>(sf + (size_t)row * DD + lane * 4);
    float ss = v.x*v.x + v.y*v.y + v.z*v.z + v.w*v.w;
#pragma unroll
    for (int off = 32; off; off >>= 1) ss += __shfl_xor(ss, off);
    if (lane == 0) {
        rinv[row] = 1.0f / fmaxf(sqrtf(ss), 1e-8f);
        const int lab = labels[row];
        const int slot = atomicAdd(&cnts[lab], 1);
        if (slot < LCAP) lists[lab * LCAP + slot] = row;
    }
}

// K2: block per class, gather listed rows, mean -> l2norm -> bf16 + arange tail.
__global__ __launch_bounds__(256) void k_proto(const float* __restrict__ sf,
                                               const float* __restrict__ rinv,
                                               const int* __restrict__ cnts,
                                               const int* __restrict__ lists,
                                               unsigned short* __restrict__ pb,
                                               float* __restrict__ outTail) {
    __shared__ float red[4];
    const int c = blockIdx.x;
    const int t = threadIdx.x;
    const int total = cnts[c];
    const int n = min(total, LCAP);
    float acc = 0.f;
    for (int j = 0; j < n; ++j) {
        const int row = lists[c * LCAP + j];
        acc += sf[(size_t)row * DD + t] * rinv[row];
    }
    const float m = acc / fmaxf((float)total, 1.0f);
    float ss = m * m;
#pragma unroll
    for (int off = 32; off; off >>= 1) ss += __shfl_xor(ss, off);
    if ((t & 63) == 0) red[t >> 6] = ss;
    __syncthreads();
    const float tot = red[0] + red[1] + red[2] + red[3];
    const float r = 1.0f / fmaxf(sqrtf(tot), 1e-8f);
    pb[(size_t)c * DD + t] = f2bf(m * r);
    if (t == 0) outTail[c] = (float)c;
}

// K3: persistent fused GEMM + qnorm + log_softmax. 512 blocks x 8 tiles,
// BM=32, 512 thr = 8 waves (qg=w>>2, cq=w&3), 2 blocks/CU.
// EXACT R8 K-loop (lockstep unit order -> B stays L2/L3-hot; ring-4,
// stage-after-barrier, counted vmcnt). Persistence adds: fire-and-forget
// stores (only drained at next tile's prologue __syncthreads, overlapped
// with STAGE 0-2 issue), raw-barrier epilogue (no hidden vmcnt(0) drains),
// and next-tile q prefetch into registers at epilogue start.
__global__ __launch_bounds__(512, 4) void k_gemm_lsm(const float* __restrict__ qf,
                                                     const unsigned short* __restrict__ pb,
                                                     float* __restrict__ out) {
    extern __shared__ char smem[];
    const int tid  = threadIdx.x;
    const int w    = tid >> 6;
    const int lane = tid & 63;
    const int g    = lane >> 4;
    const int r16  = lane & 15;
    const int qg   = w >> 2;
    const int cq   = w & 3;
    const char* pbB = (const char*)pb;

    // stage unit u (kk=u>>2 dims, cu=u&3 classes) into ring slot u&3.
    // LDS [256 c][64 B] linear dest; source pre-swizzled (s ^ (c&3)).
#define STAGE(u)                                                                         \
    {                                                                                    \
        const int kk_ = (u) >> 2, cu_ = (u) & 3;                                         \
        char* dst_ = smem + SMEM_B + ((u) & 3) * 16384 + w * 2048;                       \
        _Pragma("unroll")                                                                \
        for (int i = 0; i < 2; ++i) {                                                    \
            const int e = w * 128 + i * 64 + lane;                                       \
            const int c = e >> 2, s = e & 3;                                             \
            const char* src = pbB + ((size_t)(cu_ * 256 + c) << 9) + (kk_ << 6)          \
                                  + ((s ^ (c & 3)) << 4);                                \
            gload_lds16(src, dst_ + i * 1024);                                           \
        }                                                                                \
    }

    const int arow = tid >> 4;           // 0..31 : q row this thread stages
    const int aseg = tid & 15;           // 16 dims (64 B) each

    // initial q load (tile 0)
    float4 qv0, qv1, qv2, qv3;
    {
        const float* qrow = qf + ((size_t)blockIdx.x * NTILES * BM + arow) * (size_t)DD + aseg * 16;
        qv0 = *reinterpret_cast<const float4*>(qrow + 0);
        qv1 = *reinterpret_cast<const float4*>(qrow + 4);
        qv2 = *reinterpret_cast<const float4*>(qrow + 8);
        qv3 = *reinterpret_cast<const float4*>(qrow + 12);
    }

#pragma unroll 1
    for (int tile = 0; tile < NTILES; ++tile) {
        const size_t qbase = ((size_t)blockIdx.x * NTILES + tile) * BM;

        // ---- prologue: issue units 0..2, process preloaded q regs ----
        STAGE(0);
        STAGE(1);
        STAGE(2);
        float rinvLocal;
        {
            float ss = qv0.x*qv0.x + qv0.y*qv0.y + qv0.z*qv0.z + qv0.w*qv0.w
                     + qv1.x*qv1.x + qv1.y*qv1.y + qv1.z*qv1.z + qv1.w*qv1.w
                     + qv2.x*qv2.x + qv2.y*qv2.y + qv2.z*qv2.z + qv2.w*qv2.w
                     + qv3.x*qv3.x + qv3.y*qv3.y + qv3.z*qv3.z + qv3.w*qv3.w;
            ss += __shfl_xor(ss, 1); ss += __shfl_xor(ss, 2);
            ss += __shfl_xor(ss, 4); ss += __shfl_xor(ss, 8);
            rinvLocal = 1.0f / fmaxf(sqrtf(ss), 1e-8f);
            short8 h0, h1;
            h0[0]=(short)f2bf(qv0.x); h0[1]=(short)f2bf(qv0.y); h0[2]=(short)f2bf(qv0.z); h0[3]=(short)f2bf(qv0.w);
            h0[4]=(short)f2bf(qv1.x); h0[5]=(short)f2bf(qv1.y); h0[6]=(short)f2bf(qv1.z); h0[7]=(short)f2bf(qv1.w);
            h1[0]=(short)f2bf(qv2.x); h1[1]=(short)f2bf(qv2.y); h1[2]=(short)f2bf(qv2.z); h1[3]=(short)f2bf(qv2.w);
            h1[4]=(short)f2bf(qv3.x); h1[5]=(short)f2bf(qv3.y); h1[6]=(short)f2bf(qv3.z); h1[7]=(short)f2bf(qv3.w);
            const int x = arow & 7;
            char* aRow = smem + SMEM_A + arow * 512;
            *reinterpret_cast<short8*>(aRow + (((aseg*2)     ^ x) << 4)) = h0;
            *reinterpret_cast<short8*>(aRow + (((aseg*2 + 1) ^ x) << 4)) = h1;
        }
        __syncthreads();   // single drain point: units 0-2 + A + PREV stores + prefetch

        // hoist query frags: a[kk] = q[qg*16+r16][kk*32 + g*8 ..+8]
        short8 a[8];
        {
            const int hrow = qg * 16 + r16;
#pragma unroll
            for (int kk = 0; kk < 8; ++kk) {
                const int chunk = (kk * 4 + g) ^ (hrow & 7);
                a[kk] = *reinterpret_cast<const short8*>(smem + SMEM_A + hrow * 512 + chunk * 16);
            }
        }
        asm volatile("s_waitcnt lgkmcnt(0)" ::: "memory");
        asm volatile("s_barrier" ::: "memory");   // all hoisted; A region -> overlays

        if ((lane & 15) == 0)
            reinterpret_cast<float*>(smem + SMEM_A)[tid >> 4] = rinvLocal;

        f32x4 acc[16];
#pragma unroll
        for (int n = 0; n < 16; ++n) acc[n] = (f32x4){0.f, 0.f, 0.f, 0.f};

        // ---- main loop: 32 units, ring-4, stage-after-barrier, counted vmcnt ----
#pragma unroll
        for (int u = 0; u < 32; ++u) {
            if (u <= 29)      { asm volatile("s_waitcnt vmcnt(4)" ::: "memory"); }
            else if (u == 30) { asm volatile("s_waitcnt vmcnt(2)" ::: "memory"); }
            else              { asm volatile("s_waitcnt vmcnt(0)" ::: "memory"); }
            asm volatile("s_barrier" ::: "memory");
            if (u + 3 < 32) STAGE(u + 3);
            const char* base = smem + SMEM_B + (u & 3) * 16384;
            __builtin_amdgcn_s_setprio(1);
#pragma unroll
            for (int np = 0; np < 4; ++np) {
                const int cl = np * 64 + cq * 16 + r16;          // class within unit
                short8 b = *reinterpret_cast<const short8*>(base + cl * 64 + ((g ^ (cl & 3)) << 4));
                acc[(u & 3) * 4 + np] = __builtin_amdgcn_mfma_f32_16x16x32_bf16(b, a[u >> 2], acc[(u & 3) * 4 + np], 0, 0, 0);
            }
            __builtin_amdgcn_s_setprio(0);
        }
        asm volatile("s_waitcnt lgkmcnt(0)" ::: "memory");
        asm volatile("s_barrier" ::: "memory");   // K done; B ring -> image

        // ---- prefetch next tile's q rows (hides HBM latency under epilogue) ----
        if (tile + 1 < NTILES) {
            const float* qrowN = qf + (qbase + BM + arow) * (size_t)DD + aseg * 16;
            qv0 = *reinterpret_cast<const float4*>(qrowN + 0);
            qv1 = *reinterpret_cast<const float4*>(qrowN + 4);
            qv2 = *reinterpret_cast<const float4*>(qrowN + 8);
            qv3 = *reinterpret_cast<const float4*>(qrowN + 12);
        }

        // ---- epilogue: qinv scale + row log_softmax (raw barriers only) ----
        float* qinvLds = reinterpret_cast<float*>(smem + SMEM_A);
        float* redM = reinterpret_cast<float*>(smem + SMEM_A + 1024);   // [32][4]
        float* redS = reinterpret_cast<float*>(smem + SMEM_A + 2048);   // [32][4]
        const int myrow = qg * 16 + r16;
        const float qi = qinvLds[myrow];

#pragma unroll
        for (int n = 0; n < 16; ++n)
#pragma unroll
            for (int j = 0; j < 4; ++j) acc[n][j] *= qi;

        float m = acc[0][0];
#pragma unroll
        for (int n = 0; n < 16; ++n)
#pragma unroll
            for (int j = 0; j < 4; ++j) m = fmaxf(m, acc[n][j]);
        m = fmaxf(m, __shfl_xor(m, 16));
        m = fmaxf(m, __shfl_xor(m, 32));
        if (lane < 16) redM[myrow * 4 + cq] = m;
        asm volatile("s_waitcnt lgkmcnt(0)" ::: "memory");
        asm volatile("s_barrier" ::: "memory");
        float rowM = redM[myrow * 4 + 0];
#pragma unroll
        for (int k = 1; k < 4; ++k) rowM = fmaxf(rowM, redM[myrow * 4 + k]);

        float s = 0.f;
#pragma unroll
        for (int n = 0; n < 16; ++n)
#pragma unroll
            for (int j = 0; j < 4; ++j) s += __expf(acc[n][j] - rowM);
        s += __shfl_xor(s, 16);
        s += __shfl_xor(s, 32);
        if (lane < 16) redS[myrow * 4 + cq] = s;
        asm volatile("s_waitcnt lgkmcnt(0)" ::: "memory");
        asm volatile("s_barrier" ::: "memory");
        float rs = redS[myrow * 4 + 0];
#pragma unroll
        for (int k = 1; k < 4; ++k) rs += redS[myrow * 4 + k];
        const float lse = rowM + __logf(rs);

        // ---- stores via [16][1024] f32 image in dead B ring, 2 passes.
        // Fire-and-forget: no vmcnt drain here; drained at next prologue.
#pragma unroll
        for (int pass = 0; pass < 2; ++pass) {
            if (qg == pass) {
#pragma unroll
                for (int n = 0; n < 16; ++n) {
                    f32x4 v;
#pragma unroll
                    for (int j = 0; j < 4; ++j) v[j] = acc[n][j] - lse;
                    const int slot = n * 16 + cq * 4 + g;           // 16B slot in row
                    *reinterpret_cast<f32x4*>(smem + r16 * 4096 + ((slot ^ (r16 & 7)) << 4)) = v;
                }
            }
            asm volatile("s_waitcnt lgkmcnt(0)" ::: "memory");
            asm volatile("s_barrier" ::: "memory");
            {
                const int orow = tid >> 5;        // 0..15
                const int s0  = tid & 31;
                float* gout = out + (qbase + pass * 16 + orow) * (size_t)NC;
#pragma unroll
                for (int p = 0; p < 8; ++p) {
                    const int slot = p * 32 + s0;
                    f32x4 v = *reinterpret_cast<const f32x4*>(smem + orow * 4096 + ((slot ^ (orow & 7)) << 4));
                    *reinterpret_cast<f32x4*>(gout + slot * 4) = v;
                }
            }
            asm volatile("s_waitcnt lgkmcnt(0)" ::: "memory");
            asm volatile("s_barrier" ::: "memory");   // image reads done
        }
    }
}

extern "C" void kernel_launch(void* const* d_in, const int* in_sizes, int n_in,
                              void* d_out, int out_size, void* d_ws, size_t ws_size,
                              hipStream_t stream) {
    const float* sf     = (const float*)d_in[0];
    const int*   labels = (const int*)d_in[1];
    const float* qf     = (const float*)d_in[2];
    float* out = (float*)d_out;

    char* ws = (char*)d_ws;
    float* rinv         = (float*)ws;                          // 256 KiB
    unsigned short* pb  = (unsigned short*)(ws + 262144);      // 512 KiB
    int* cnts           = (int*)(ws + 786432);                 // 4 KiB
    int* lists          = (int*)(ws + 790528);                 // 512 KiB

    hipFuncSetAttribute(reinterpret_cast<const void*>(k_gemm_lsm),
                        hipFuncAttributeMaxDynamicSharedMemorySize, SMEM_TOTAL);

    hipMemsetAsync(cnts, 0, NC * sizeof(int), stream);

    k_count<<<NS / 4, 256, 0, stream>>>(sf, labels, rinv, cnts, lists);

    float* outTail = out + (size_t)out_size - NC;
    k_proto<<<NC, 256, 0, stream>>>(sf, rinv, cnts, lists, pb, outTail);

    k_gemm_lsm<<<NBLK, 512, SMEM_TOTAL, stream>>>(qf, pb, out);
}

// Round 11
// 301.937 us; speedup vs baseline: 2.5014x; 2.3814x over previous
//
#include <hip/hip_runtime.h>
#include <hip/hip_bf16.h>

#define NS 65536
#define NQ 131072
#define DD 256
#define NC 1024
#define BM 32
#define LCAP 128

typedef __attribute__((ext_vector_type(8))) short short8;
typedef __attribute__((ext_vector_type(4))) float f32x4;

// LDS carve (bytes): B ring 4 x 16384 at 0; A [32][512] at 65536. Total 80 KB
// -> 2 blocks/CU. After A-hoist the A region is overlaid with qinv(+0),
// redM(+1024), redS(+2048). Stores go DIRECTLY from acc (full 64-B lines:
// 4-lane g-cluster writes 4x16B contiguous, 64B-aligned) -- no LDS image.
#define SMEM_B     0
#define SMEM_A     65536
#define SMEM_TOTAL 81920

static __device__ __forceinline__ unsigned short f2bf(float f) {
    unsigned int u = __float_as_uint(f);
    u += 0x7fffu + ((u >> 16) & 1u);          // round-to-nearest-even
    return (unsigned short)(u >> 16);
}

static __device__ __forceinline__ void gload_lds16(const void* src, void* dst) {
    using GPtr = const __attribute__((address_space(1))) unsigned int*;
    using LPtr = __attribute__((address_space(3))) unsigned int*;
    GPtr g = reinterpret_cast<GPtr>(reinterpret_cast<uintptr_t>(src));
    LPtr l = reinterpret_cast<LPtr>(static_cast<unsigned int>(reinterpret_cast<uintptr_t>(dst)));
    __builtin_amdgcn_global_load_lds(g, l, 16, 0, 0);
}

// K1: one sf pass: per-row rinv (wave per row) + per-class compact row list.
__global__ __launch_bounds__(256) void k_count(const float* __restrict__ sf,
                                               const int* __restrict__ labels,
                                               float* __restrict__ rinv,
                                               int* __restrict__ cnts,
                                               int* __restrict__ lists) {
    const int row  = (blockIdx.x << 2) + (threadIdx.x >> 6);
    const int lane = threadIdx.x & 63;
    float4 v = *reinterpret_cast<const float4*>(sf + (size_t)row * DD + lane * 4);
    float ss = v.x*v.x + v.y*v.y + v.z*v.z + v.w*v.w;
#pragma unroll
    for (int off = 32; off; off >>= 1) ss += __shfl_xor(ss, off);
    if (lane == 0) {
        rinv[row] = 1.0f / fmaxf(sqrtf(ss), 1e-8f);
        const int lab = labels[row];
        const int slot = atomicAdd(&cnts[lab], 1);
        if (slot < LCAP) lists[lab * LCAP + slot] = row;
    }
}

// K2: block per class, gather listed rows, mean -> l2norm -> bf16 + arange tail.
__global__ __launch_bounds__(256) void k_proto(const float* __restrict__ sf,
                                               const float* __restrict__ rinv,
                                               const int* __restrict__ cnts,
                                               const int* __restrict__ lists,
                                               unsigned short* __restrict__ pb,
                                               float* __restrict__ outTail) {
    __shared__ float red[4];
    const int c = blockIdx.x;
    const int t = threadIdx.x;
    const int total = cnts[c];
    const int n = min(total, LCAP);
    float acc = 0.f;
#pragma unroll 2
    for (int j = 0; j < n; ++j) {
        const int row = lists[c * LCAP + j];
        acc += sf[(size_t)row * DD + t] * rinv[row];
    }
    const float m = acc / fmaxf((float)total, 1.0f);
    float ss = m * m;
#pragma unroll
    for (int off = 32; off; off >>= 1) ss += __shfl_xor(ss, off);
    if ((t & 63) == 0) red[t >> 6] = ss;
    __syncthreads();
    const float tot = red[0] + red[1] + red[2] + red[3];
    const float r = 1.0f / fmaxf(sqrtf(tot), 1e-8f);
    pb[(size_t)c * DD + t] = f2bf(m * r);
    if (t == 0) outTail[c] = (float)c;
}

// K3: fused GEMM + qnorm + log_softmax. 512 thr = 8 waves (qg=w>>2, cq=w&3),
// BM=32, 2 blocks/CU, fresh-block dispatch (8192 blocks -- proven best).
// 32 stage-units of 16 KB (unit u: kk=u>>2 dims, cu=u&3 classes), ring-4,
// STAGE issued AFTER the barrier (race-free), counted vmcnt(4/2/0).
// Thread (qg,cq,g,r16) reg (n,j) holds
// logits[q=qg*16+r16][class = n*64 + cq*16 + g*4 + j] -> direct full-line
// stores from acc (4-lane g-cluster = one aligned 64-B line), no LDS image.
__global__ __launch_bounds__(512, 4) void k_gemm_lsm(const float* __restrict__ qf,
                                                     const unsigned short* __restrict__ pb,
                                                     float* __restrict__ out) {
    extern __shared__ char smem[];
    const int tid  = threadIdx.x;
    const int w    = tid >> 6;
    const int lane = tid & 63;
    const int g    = lane >> 4;
    const int r16  = lane & 15;
    const int qg   = w >> 2;
    const int cq   = w & 3;
    const size_t qbase = (size_t)blockIdx.x * BM;
    const char* pbB = (const char*)pb;

    // stage unit u: LDS [256 c][64 B] linear dest; SOURCE pre-swizzled so reads
    // at slot' = g ^ (c&3) are balanced (involution: s ^ (c&3)).
#define STAGE(u)                                                                         \
    {                                                                                    \
        const int kk_ = (u) >> 2, cu_ = (u) & 3;                                         \
        char* dst_ = smem + SMEM_B + ((u) & 3) * 16384 + w * 2048;                       \
        _Pragma("unroll")                                                                \
        for (int i = 0; i < 2; ++i) {                                                    \
            const int e = w * 128 + i * 64 + lane;                                       \
            const int c = e >> 2, s = e & 3;                                             \
            const char* src = pbB + ((size_t)(cu_ * 256 + c) << 9) + (kk_ << 6)          \
                                  + ((s ^ (c & 3)) << 4);                                \
            gload_lds16(src, dst_ + i * 1024);                                           \
        }                                                                                \
    }

    // prologue: issue units 0..2, then cooperative A-stage (32 rows x 256 dims)
    STAGE(0);
    STAGE(1);
    STAGE(2);
    float rinvLocal = 0.f;
    {
        const int row = tid >> 4;            // 0..31
        const int seg = tid & 15;            // 16 dims (64 B) each
        const float* qrow = qf + (qbase + row) * (size_t)DD + seg * 16;
        float4 f0 = *reinterpret_cast<const float4*>(qrow + 0);
        float4 f1 = *reinterpret_cast<const float4*>(qrow + 4);
        float4 f2 = *reinterpret_cast<const float4*>(qrow + 8);
        float4 f3 = *reinterpret_cast<const float4*>(qrow + 12);
        float ss = f0.x*f0.x + f0.y*f0.y + f0.z*f0.z + f0.w*f0.w
                 + f1.x*f1.x + f1.y*f1.y + f1.z*f1.z + f1.w*f1.w
                 + f2.x*f2.x + f2.y*f2.y + f2.z*f2.z + f2.w*f2.w
                 + f3.x*f3.x + f3.y*f3.y + f3.z*f3.z + f3.w*f3.w;
        ss += __shfl_xor(ss, 1); ss += __shfl_xor(ss, 2);
        ss += __shfl_xor(ss, 4); ss += __shfl_xor(ss, 8);
        rinvLocal = 1.0f / fmaxf(sqrtf(ss), 1e-8f);
        short8 h0, h1;
        h0[0]=(short)f2bf(f0.x); h0[1]=(short)f2bf(f0.y); h0[2]=(short)f2bf(f0.z); h0[3]=(short)f2bf(f0.w);
        h0[4]=(short)f2bf(f1.x); h0[5]=(short)f2bf(f1.y); h0[6]=(short)f2bf(f1.z); h0[7]=(short)f2bf(f1.w);
        h1[0]=(short)f2bf(f2.x); h1[1]=(short)f2bf(f2.y); h1[2]=(short)f2bf(f2.z); h1[3]=(short)f2bf(f2.w);
        h1[4]=(short)f2bf(f3.x); h1[5]=(short)f2bf(f3.y); h1[6]=(short)f2bf(f3.z); h1[7]=(short)f2bf(f3.w);
        const int x = row & 7;
        char* aRow = smem + SMEM_A + row * 512;
        *reinterpret_cast<short8*>(aRow + (((seg*2)     ^ x) << 4)) = h0;
        *reinterpret_cast<short8*>(aRow + (((seg*2 + 1) ^ x) << 4)) = h1;
    }
    __syncthreads();   // full drain: units 0-2 + A all in LDS (prologue only)

    // hoist query frags: a[kk] = q[qg*16+r16][kk*32 + g*8 ..+8]; 32 VGPRs
    short8 a[8];
    {
        const int row = qg * 16 + r16;
#pragma unroll
        for (int kk = 0; kk < 8; ++kk) {
            const int chunk = (kk * 4 + g) ^ (row & 7);
            a[kk] = *reinterpret_cast<const short8*>(smem + SMEM_A + row * 512 + chunk * 16);
        }
    }
    __syncthreads();   // all waves hoisted; A region free for overlays

    if ((lane & 15) == 0)
        reinterpret_cast<float*>(smem + SMEM_A)[tid >> 4] = rinvLocal;

    f32x4 acc[16];
#pragma unroll
    for (int n = 0; n < 16; ++n) acc[n] = (f32x4){0.f, 0.f, 0.f, 0.f};

    // ---- main loop: 32 units, ring-4, stage-after-barrier, counted vmcnt ----
#pragma unroll
    for (int u = 0; u < 32; ++u) {
        if (u <= 29)      { asm volatile("s_waitcnt vmcnt(4)" ::: "memory"); }
        else if (u == 30) { asm volatile("s_waitcnt vmcnt(2)" ::: "memory"); }
        else              { asm volatile("s_waitcnt vmcnt(0)" ::: "memory"); }
        asm volatile("s_barrier" ::: "memory");
        if (u + 3 < 32) STAGE(u + 3);
        const int kk = u >> 2, cu = u & 3;
        const char* base = smem + SMEM_B + (u & 3) * 16384;
        __builtin_amdgcn_s_setprio(1);
#pragma unroll
        for (int np = 0; np < 4; ++np) {
            const int cl = np * 64 + cq * 16 + r16;          // class within unit
            short8 b = *reinterpret_cast<const short8*>(base + cl * 64 + ((g ^ (cl & 3)) << 4));
            acc[cu * 4 + np] = __builtin_amdgcn_mfma_f32_16x16x32_bf16(b, a[kk], acc[cu * 4 + np], 0, 0, 0);
        }
        __builtin_amdgcn_s_setprio(0);
    }

    // ---- epilogue: qinv scale + row log_softmax (no post-K barrier needed:
    // B ring is dead and never reused; reductions use their own barriers) ----
    float* qinvLds = reinterpret_cast<float*>(smem + SMEM_A);
    float* redM = reinterpret_cast<float*>(smem + SMEM_A + 1024);   // [32][4]
    float* redS = reinterpret_cast<float*>(smem + SMEM_A + 2048);   // [32][4]
    const int myrow = qg * 16 + r16;
    const float qi = qinvLds[myrow];

#pragma unroll
    for (int n = 0; n < 16; ++n)
#pragma unroll
        for (int j = 0; j < 4; ++j) acc[n][j] *= qi;

    float m = acc[0][0];
#pragma unroll
    for (int n = 0; n < 16; ++n)
#pragma unroll
        for (int j = 0; j < 4; ++j) m = fmaxf(m, acc[n][j]);
    m = fmaxf(m, __shfl_xor(m, 16));
    m = fmaxf(m, __shfl_xor(m, 32));
    if (lane < 16) redM[myrow * 4 + cq] = m;
    __syncthreads();
    float rowM = redM[myrow * 4 + 0];
#pragma unroll
    for (int k = 1; k < 4; ++k) rowM = fmaxf(rowM, redM[myrow * 4 + k]);

    float s = 0.f;
#pragma unroll
    for (int n = 0; n < 16; ++n)
#pragma unroll
        for (int j = 0; j < 4; ++j) s += __expf(acc[n][j] - rowM);
    s += __shfl_xor(s, 16);
    s += __shfl_xor(s, 32);
    if (lane < 16) redS[myrow * 4 + cq] = s;
    __syncthreads();
    float rs = redS[myrow * 4 + 0];
#pragma unroll
    for (int k = 1; k < 4; ++k) rs += redS[myrow * 4 + k];
    const float lse = rowM + __logf(rs);

    // ---- direct stores from acc: thread writes 16 dwordx4, each 4-lane
    // g-cluster covers one aligned 64-B line (full-line writes, no RMW) ----
    float* orow = out + (qbase + myrow) * (size_t)NC + cq * 16 + g * 4;
#pragma unroll
    for (int n = 0; n < 16; ++n) {
        f32x4 v;
#pragma unroll
        for (int j = 0; j < 4; ++j) v[j] = acc[n][j] - lse;
        *reinterpret_cast<f32x4*>(orow + n * 64) = v;
    }
}

extern "C" void kernel_launch(void* const* d_in, const int* in_sizes, int n_in,
                              void* d_out, int out_size, void* d_ws, size_t ws_size,
                              hipStream_t stream) {
    const float* sf     = (const float*)d_in[0];
    const int*   labels = (const int*)d_in[1];
    const float* qf     = (const float*)d_in[2];
    float* out = (float*)d_out;

    char* ws = (char*)d_ws;
    float* rinv         = (float*)ws;                          // 256 KiB
    unsigned short* pb  = (unsigned short*)(ws + 262144);      // 512 KiB
    int* cnts           = (int*)(ws + 786432);                 // 4 KiB
    int* lists          = (int*)(ws + 790528);                 // 512 KiB

    hipFuncSetAttribute(reinterpret_cast<const void*>(k_gemm_lsm),
                        hipFuncAttributeMaxDynamicSharedMemorySize, SMEM_TOTAL);

    hipMemsetAsync(cnts, 0, NC * sizeof(int), stream);

    k_count<<<NS / 4, 256, 0, stream>>>(sf, labels, rinv, cnts, lists);

    float* outTail = out + (size_t)out_size - NC;
    k_proto<<<NC, 256, 0, stream>>>(sf, rinv, cnts, lists, pb, outTail);

    k_gemm_lsm<<<NQ / BM, 512, SMEM_TOTAL, stream>>>(qf, pb, out);
}

// Round 12
// 265.709 us; speedup vs baseline: 2.8424x; 1.1363x over previous
//
#include <hip/hip_runtime.h>
#include <hip/hip_bf16.h>

#define NS 65536
#define NQ 131072
#define DD 256
#define NC 1024
#define BM 32
#define LCAP 128

typedef __attribute__((ext_vector_type(8))) short short8;
typedef __attribute__((ext_vector_type(4))) float f32x4;

// LDS carve (bytes): B ring 4 x 16384 at 0; A [32][512] at 65536. Total 80 KB
// -> 2 blocks/CU. After A-hoist the A region is overlaid with qinv(+0),
// redM(+1024), redS(+2048). After the K-loop the B ring is overlaid with a
// [16][1024] f32 output image (two passes) -- proven faster than direct stores.
#define SMEM_B     0
#define SMEM_A     65536
#define SMEM_TOTAL 81920

static __device__ __forceinline__ unsigned short f2bf(float f) {
    unsigned int u = __float_as_uint(f);
    u += 0x7fffu + ((u >> 16) & 1u);          // round-to-nearest-even
    return (unsigned short)(u >> 16);
}

static __device__ __forceinline__ void gload_lds16(const void* src, void* dst) {
    using GPtr = const __attribute__((address_space(1))) unsigned int*;
    using LPtr = __attribute__((address_space(3))) unsigned int*;
    GPtr g = reinterpret_cast<GPtr>(reinterpret_cast<uintptr_t>(src));
    LPtr l = reinterpret_cast<LPtr>(static_cast<unsigned int>(reinterpret_cast<uintptr_t>(dst)));
    __builtin_amdgcn_global_load_lds(g, l, 16, 0, 0);
}

// K1: one sf pass: per-row rinv (wave per row) + per-class compact row list.
__global__ __launch_bounds__(256) void k_count(const float* __restrict__ sf,
                                               const int* __restrict__ labels,
                                               float* __restrict__ rinv,
                                               int* __restrict__ cnts,
                                               int* __restrict__ lists) {
    const int row  = (blockIdx.x << 2) + (threadIdx.x >> 6);
    const int lane = threadIdx.x & 63;
    float4 v = *reinterpret_cast<const float4*>(sf + (size_t)row * DD + lane * 4);
    float ss = v.x*v.x + v.y*v.y + v.z*v.z + v.w*v.w;
#pragma unroll
    for (int off = 32; off; off >>= 1) ss += __shfl_xor(ss, off);
    if (lane == 0) {
        rinv[row] = 1.0f / fmaxf(sqrtf(ss), 1e-8f);
        const int lab = labels[row];
        const int slot = atomicAdd(&cnts[lab], 1);
        if (slot < LCAP) lists[lab * LCAP + slot] = row;
    }
}

// K2: block per class, gather listed rows (4 independent acc chains for
// memory-level parallelism), mean -> l2norm -> bf16 + arange tail.
__global__ __launch_bounds__(256) void k_proto(const float* __restrict__ sf,
                                               const float* __restrict__ rinv,
                                               const int* __restrict__ cnts,
                                               const int* __restrict__ lists,
                                               unsigned short* __restrict__ pb,
                                               float* __restrict__ outTail) {
    __shared__ float red[4];
    const int c = blockIdx.x;
    const int t = threadIdx.x;
    const int total = cnts[c];
    const int n = min(total, LCAP);
    float a0 = 0.f, a1 = 0.f, a2 = 0.f, a3 = 0.f;
    int j = 0;
    for (; j + 3 < n; j += 4) {
        const int r0 = lists[c * LCAP + j + 0];
        const int r1 = lists[c * LCAP + j + 1];
        const int r2 = lists[c * LCAP + j + 2];
        const int r3 = lists[c * LCAP + j + 3];
        a0 += sf[(size_t)r0 * DD + t] * rinv[r0];
        a1 += sf[(size_t)r1 * DD + t] * rinv[r1];
        a2 += sf[(size_t)r2 * DD + t] * rinv[r2];
        a3 += sf[(size_t)r3 * DD + t] * rinv[r3];
    }
    for (; j < n; ++j) {
        const int r0 = lists[c * LCAP + j];
        a0 += sf[(size_t)r0 * DD + t] * rinv[r0];
    }
    const float acc = (a0 + a1) + (a2 + a3);
    const float m = acc / fmaxf((float)total, 1.0f);
    float ss = m * m;
#pragma unroll
    for (int off = 32; off; off >>= 1) ss += __shfl_xor(ss, off);
    if ((t & 63) == 0) red[t >> 6] = ss;
    __syncthreads();
    const float tot = red[0] + red[1] + red[2] + red[3];
    const float r = 1.0f / fmaxf(sqrtf(tot), 1e-8f);
    pb[(size_t)c * DD + t] = f2bf(m * r);
    if (t == 0) outTail[c] = (float)c;
}

// K3: fused GEMM + qnorm + log_softmax. EXACT R8 structure (best: 279 us):
// 512 thr = 8 waves (qg=w>>2, cq=w&3), BM=32, 2 blocks/CU, fresh dispatch,
// 32 stage-units of 16 KB, ring-4, stage-after-barrier, counted vmcnt(4/2/0),
// LDS-image epilogue. Delta vs R8: epilogue uses raw lgkmcnt-only barriers so
// global stores of pass 0 / pass 1 drain outside the block's critical path.
__global__ __launch_bounds__(512, 4) void k_gemm_lsm(const float* __restrict__ qf,
                                                     const unsigned short* __restrict__ pb,
                                                     float* __restrict__ out) {
    extern __shared__ char smem[];
    const int tid  = threadIdx.x;
    const int w    = tid >> 6;
    const int lane = tid & 63;
    const int g    = lane >> 4;
    const int r16  = lane & 15;
    const int qg   = w >> 2;
    const int cq   = w & 3;
    const size_t qbase = (size_t)blockIdx.x * BM;
    const char* pbB = (const char*)pb;

    // stage unit u (kk=u>>2 dims, cu=u&3 classes) into ring slot u&3.
    // LDS [256 c][64 B] linear dest; source pre-swizzled (s ^ (c&3)).
#define STAGE(u)                                                                         \
    {                                                                                    \
        const int kk_ = (u) >> 2, cu_ = (u) & 3;                                         \
        char* dst_ = smem + SMEM_B + ((u) & 3) * 16384 + w * 2048;                       \
        _Pragma("unroll")                                                                \
        for (int i = 0; i < 2; ++i) {                                                    \
            const int e = w * 128 + i * 64 + lane;                                       \
            const int c = e >> 2, s = e & 3;                                             \
            const char* src = pbB + ((size_t)(cu_ * 256 + c) << 9) + (kk_ << 6)          \
                                  + ((s ^ (c & 3)) << 4);                                \
            gload_lds16(src, dst_ + i * 1024);                                           \
        }                                                                                \
    }

    // prologue: issue units 0..2, then cooperative A-stage (32 rows x 256 dims)
    STAGE(0);
    STAGE(1);
    STAGE(2);
    float rinvLocal = 0.f;
    {
        const int row = tid >> 4;            // 0..31
        const int seg = tid & 15;            // 16 dims (64 B) each
        const float* qrow = qf + (qbase + row) * (size_t)DD + seg * 16;
        float4 f0 = *reinterpret_cast<const float4*>(qrow + 0);
        float4 f1 = *reinterpret_cast<const float4*>(qrow + 4);
        float4 f2 = *reinterpret_cast<const float4*>(qrow + 8);
        float4 f3 = *reinterpret_cast<const float4*>(qrow + 12);
        float ss = f0.x*f0.x + f0.y*f0.y + f0.z*f0.z + f0.w*f0.w
                 + f1.x*f1.x + f1.y*f1.y + f1.z*f1.z + f1.w*f1.w
                 + f2.x*f2.x + f2.y*f2.y + f2.z*f2.z + f2.w*f2.w
                 + f3.x*f3.x + f3.y*f3.y + f3.z*f3.z + f3.w*f3.w;
        ss += __shfl_xor(ss, 1); ss += __shfl_xor(ss, 2);
        ss += __shfl_xor(ss, 4); ss += __shfl_xor(ss, 8);
        rinvLocal = 1.0f / fmaxf(sqrtf(ss), 1e-8f);
        short8 h0, h1;
        h0[0]=(short)f2bf(f0.x); h0[1]=(short)f2bf(f0.y); h0[2]=(short)f2bf(f0.z); h0[3]=(short)f2bf(f0.w);
        h0[4]=(short)f2bf(f1.x); h0[5]=(short)f2bf(f1.y); h0[6]=(short)f2bf(f1.z); h0[7]=(short)f2bf(f1.w);
        h1[0]=(short)f2bf(f2.x); h1[1]=(short)f2bf(f2.y); h1[2]=(short)f2bf(f2.z); h1[3]=(short)f2bf(f2.w);
        h1[4]=(short)f2bf(f3.x); h1[5]=(short)f2bf(f3.y); h1[6]=(short)f2bf(f3.z); h1[7]=(short)f2bf(f3.w);
        const int x = row & 7;
        char* aRow = smem + SMEM_A + row * 512;
        *reinterpret_cast<short8*>(aRow + (((seg*2)     ^ x) << 4)) = h0;
        *reinterpret_cast<short8*>(aRow + (((seg*2 + 1) ^ x) << 4)) = h1;
    }
    __syncthreads();   // full drain: units 0-2 + A all in LDS (prologue only)

    // hoist query frags: a[kk] = q[qg*16+r16][kk*32 + g*8 ..+8]; 32 VGPRs
    short8 a[8];
    {
        const int row = qg * 16 + r16;
#pragma unroll
        for (int kk = 0; kk < 8; ++kk) {
            const int chunk = (kk * 4 + g) ^ (row & 7);
            a[kk] = *reinterpret_cast<const short8*>(smem + SMEM_A + row * 512 + chunk * 16);
        }
    }
    __syncthreads();   // all waves hoisted; A region free for overlays

    if ((lane & 15) == 0)
        reinterpret_cast<float*>(smem + SMEM_A)[tid >> 4] = rinvLocal;

    f32x4 acc[16];
#pragma unroll
    for (int n = 0; n < 16; ++n) acc[n] = (f32x4){0.f, 0.f, 0.f, 0.f};

    // ---- main loop: 32 units, ring-4, stage-after-barrier, counted vmcnt ----
#pragma unroll
    for (int u = 0; u < 32; ++u) {
        if (u <= 29)      { asm volatile("s_waitcnt vmcnt(4)" ::: "memory"); }
        else if (u == 30) { asm volatile("s_waitcnt vmcnt(2)" ::: "memory"); }
        else              { asm volatile("s_waitcnt vmcnt(0)" ::: "memory"); }
        asm volatile("s_barrier" ::: "memory");
        if (u + 3 < 32) STAGE(u + 3);
        const int kk = u >> 2, cu = u & 3;
        const char* base = smem + SMEM_B + (u & 3) * 16384;
        __builtin_amdgcn_s_setprio(1);
#pragma unroll
        for (int np = 0; np < 4; ++np) {
            const int cl = np * 64 + cq * 16 + r16;          // class within unit
            short8 b = *reinterpret_cast<const short8*>(base + cl * 64 + ((g ^ (cl & 3)) << 4));
            acc[cu * 4 + np] = __builtin_amdgcn_mfma_f32_16x16x32_bf16(b, a[kk], acc[cu * 4 + np], 0, 0, 0);
        }
        __builtin_amdgcn_s_setprio(0);
    }
    asm volatile("s_waitcnt lgkmcnt(0)" ::: "memory");
    asm volatile("s_barrier" ::: "memory");   // K done; B ring becomes image

    // ---- epilogue: qinv scale + row log_softmax (raw lgkm barriers only) ----
    float* qinvLds = reinterpret_cast<float*>(smem + SMEM_A);
    float* redM = reinterpret_cast<float*>(smem + SMEM_A + 1024);   // [32][4]
    float* redS = reinterpret_cast<float*>(smem + SMEM_A + 2048);   // [32][4]
    const int myrow = qg * 16 + r16;
    const float qi = qinvLds[myrow];

#pragma unroll
    for (int n = 0; n < 16; ++n)
#pragma unroll
        for (int j = 0; j < 4; ++j) acc[n][j] *= qi;

    float m = acc[0][0];
#pragma unroll
    for (int n = 0; n < 16; ++n)
#pragma unroll
        for (int j = 0; j < 4; ++j) m = fmaxf(m, acc[n][j]);
    m = fmaxf(m, __shfl_xor(m, 16));
    m = fmaxf(m, __shfl_xor(m, 32));
    if (lane < 16) redM[myrow * 4 + cq] = m;
    asm volatile("s_waitcnt lgkmcnt(0)" ::: "memory");
    asm volatile("s_barrier" ::: "memory");
    float rowM = redM[myrow * 4 + 0];
#pragma unroll
    for (int k = 1; k < 4; ++k) rowM = fmaxf(rowM, redM[myrow * 4 + k]);

    float s = 0.f;
#pragma unroll
    for (int n = 0; n < 16; ++n)
#pragma unroll
        for (int j = 0; j < 4; ++j) s += __expf(acc[n][j] - rowM);
    s += __shfl_xor(s, 16);
    s += __shfl_xor(s, 32);
    if (lane < 16) redS[myrow * 4 + cq] = s;
    asm volatile("s_waitcnt lgkmcnt(0)" ::: "memory");
    asm volatile("s_barrier" ::: "memory");
    float rs = redS[myrow * 4 + 0];
#pragma unroll
    for (int k = 1; k < 4; ++k) rs += redS[myrow * 4 + k];
    const float lse = rowM + __logf(rs);

    // ---- stores via [16][1024] f32 image in dead B ring, 2 passes.
    // Raw lgkm barriers: global stores drain outside the critical path.
#pragma unroll
    for (int pass = 0; pass < 2; ++pass) {
        if (qg == pass) {
#pragma unroll
            for (int n = 0; n < 16; ++n) {
                f32x4 v;
#pragma unroll
                for (int j = 0; j < 4; ++j) v[j] = acc[n][j] - lse;
                const int slot = n * 16 + cq * 4 + g;           // 16B slot in row
                *reinterpret_cast<f32x4*>(smem + r16 * 4096 + ((slot ^ (r16 & 7)) << 4)) = v;
            }
        }
        asm volatile("s_waitcnt lgkmcnt(0)" ::: "memory");
        asm volatile("s_barrier" ::: "memory");
        {
            const int orow = tid >> 5;        // 0..15
            const int s0  = tid & 31;
            float* gout = out + (qbase + pass * 16 + orow) * (size_t)NC;
#pragma unroll
            for (int p = 0; p < 8; ++p) {
                const int slot = p * 32 + s0;
                f32x4 v = *reinterpret_cast<const f32x4*>(smem + orow * 4096 + ((slot ^ (orow & 7)) << 4));
                *reinterpret_cast<f32x4*>(gout + slot * 4) = v;
            }
        }
        asm volatile("s_waitcnt lgkmcnt(0)" ::: "memory");
        asm volatile("s_barrier" ::: "memory");   // image reads done
    }
}

extern "C" void kernel_launch(void* const* d_in, const int* in_sizes, int n_in,
                              void* d_out, int out_size, void* d_ws, size_t ws_size,
                              hipStream_t stream) {
    const float* sf     = (const float*)d_in[0];
    const int*   labels = (const int*)d_in[1];
    const float* qf     = (const float*)d_in[2];
    float* out = (float*)d_out;

    char* ws = (char*)d_ws;
    float* rinv         = (float*)ws;                          // 256 KiB
    unsigned short* pb  = (unsigned short*)(ws + 262144);      // 512 KiB
    int* cnts           = (int*)(ws + 786432);                 // 4 KiB
    int* lists          = (int*)(ws + 790528);                 // 512 KiB

    hipFuncSetAttribute(reinterpret_cast<const void*>(k_gemm_lsm),
                        hipFuncAttributeMaxDynamicSharedMemorySize, SMEM_TOTAL);

    hipMemsetAsync(cnts, 0, NC * sizeof(int), stream);

    k_count<<<NS / 4, 256, 0, stream>>>(sf, labels, rinv, cnts, lists);

    float* outTail = out + (size_t)out_size - NC;
    k_proto<<<NC, 256, 0, stream>>>(sf, rinv, cnts, lists, pb, outTail);

    k_gemm_lsm<<<NQ / BM, 512, SMEM_TOTAL, stream>>>(qf, pb, out);
}

// Round 13
// 265.615 us; speedup vs baseline: 2.8434x; 1.0004x over previous
//
#include <hip/hip_runtime.h>
#include <hip/hip_bf16.h>

#define NS 65536
#define NQ 131072
#define DD 256
#define NC 1024
#define BM 32
#define LCAP 128

typedef __attribute__((ext_vector_type(8))) short short8;
typedef __attribute__((ext_vector_type(4))) float f32x4;

// LDS carve (bytes): B ring 4 x 16384 at 0; A [32][512] at 65536. Total 80 KB
// -> 2 blocks/CU. After A-hoist the A region is overlaid with qinv(+0),
// redM(+1024), redS(+2048). After the K-loop the B ring is overlaid with a
// [16][1024] f32 output image (two passes) -- proven faster than direct stores.
#define SMEM_B     0
#define SMEM_A     65536
#define SMEM_TOTAL 81920

static __device__ __forceinline__ unsigned short f2bf(float f) {
    unsigned int u = __float_as_uint(f);
    u += 0x7fffu + ((u >> 16) & 1u);          // round-to-nearest-even
    return (unsigned short)(u >> 16);
}

static __device__ __forceinline__ void gload_lds16(const void* src, void* dst) {
    using GPtr = const __attribute__((address_space(1))) unsigned int*;
    using LPtr = __attribute__((address_space(3))) unsigned int*;
    GPtr g = reinterpret_cast<GPtr>(reinterpret_cast<uintptr_t>(src));
    LPtr l = reinterpret_cast<LPtr>(static_cast<unsigned int>(reinterpret_cast<uintptr_t>(dst)));
    __builtin_amdgcn_global_load_lds(g, l, 16, 0, 0);
}

// K1: one sf pass: per-row rinv (wave per row) + per-class compact row list.
__global__ __launch_bounds__(256) void k_count(const float* __restrict__ sf,
                                               const int* __restrict__ labels,
                                               float* __restrict__ rinv,
                                               int* __restrict__ cnts,
                                               int* __restrict__ lists) {
    const int row  = (blockIdx.x << 2) + (threadIdx.x >> 6);
    const int lane = threadIdx.x & 63;
    float4 v = *reinterpret_cast<const float4*>(sf + (size_t)row * DD + lane * 4);
    float ss = v.x*v.x + v.y*v.y + v.z*v.z + v.w*v.w;
#pragma unroll
    for (int off = 32; off; off >>= 1) ss += __shfl_xor(ss, off);
    if (lane == 0) {
        rinv[row] = 1.0f / fmaxf(sqrtf(ss), 1e-8f);
        const int lab = labels[row];
        const int slot = atomicAdd(&cnts[lab], 1);
        if (slot < LCAP) lists[lab * LCAP + slot] = row;
    }
}

// K2: block per class, gather listed rows (4 independent acc chains for
// memory-level parallelism), mean -> l2norm -> bf16 + arange tail.
__global__ __launch_bounds__(256) void k_proto(const float* __restrict__ sf,
                                               const float* __restrict__ rinv,
                                               const int* __restrict__ cnts,
                                               const int* __restrict__ lists,
                                               unsigned short* __restrict__ pb,
                                               float* __restrict__ outTail) {
    __shared__ float red[4];
    const int c = blockIdx.x;
    const int t = threadIdx.x;
    const int total = cnts[c];
    const int n = min(total, LCAP);
    float a0 = 0.f, a1 = 0.f, a2 = 0.f, a3 = 0.f;
    int j = 0;
    for (; j + 3 < n; j += 4) {
        const int r0 = lists[c * LCAP + j + 0];
        const int r1 = lists[c * LCAP + j + 1];
        const int r2 = lists[c * LCAP + j + 2];
        const int r3 = lists[c * LCAP + j + 3];
        a0 += sf[(size_t)r0 * DD + t] * rinv[r0];
        a1 += sf[(size_t)r1 * DD + t] * rinv[r1];
        a2 += sf[(size_t)r2 * DD + t] * rinv[r2];
        a3 += sf[(size_t)r3 * DD + t] * rinv[r3];
    }
    for (; j < n; ++j) {
        const int r0 = lists[c * LCAP + j];
        a0 += sf[(size_t)r0 * DD + t] * rinv[r0];
    }
    const float acc = (a0 + a1) + (a2 + a3);
    const float m = acc / fmaxf((float)total, 1.0f);
    float ss = m * m;
#pragma unroll
    for (int off = 32; off; off >>= 1) ss += __shfl_xor(ss, off);
    if ((t & 63) == 0) red[t >> 6] = ss;
    __syncthreads();
    const float tot = red[0] + red[1] + red[2] + red[3];
    const float r = 1.0f / fmaxf(sqrtf(tot), 1e-8f);
    pb[(size_t)c * DD + t] = f2bf(m * r);
    if (t == 0) outTail[c] = (float)c;
}

// K3: fused GEMM + qnorm + log_softmax. EXACT R8 structure (best: 279 us):
// 512 thr = 8 waves (qg=w>>2, cq=w&3), BM=32, 2 blocks/CU, fresh dispatch,
// 32 stage-units of 16 KB, ring-4, stage-after-barrier, counted vmcnt(4/2/0),
// LDS-image epilogue. Delta vs R8: epilogue uses raw lgkmcnt-only barriers so
// global stores of pass 0 / pass 1 drain outside the block's critical path.
__global__ __launch_bounds__(512, 4) void k_gemm_lsm(const float* __restrict__ qf,
                                                     const unsigned short* __restrict__ pb,
                                                     float* __restrict__ out) {
    extern __shared__ char smem[];
    const int tid  = threadIdx.x;
    const int w    = tid >> 6;
    const int lane = tid & 63;
    const int g    = lane >> 4;
    const int r16  = lane & 15;
    const int qg   = w >> 2;
    const int cq   = w & 3;
    const size_t qbase = (size_t)blockIdx.x * BM;
    const char* pbB = (const char*)pb;

    // stage unit u (kk=u>>2 dims, cu=u&3 classes) into ring slot u&3.
    // LDS [256 c][64 B] linear dest; source pre-swizzled (s ^ (c&3)).
#define STAGE(u)                                                                         \
    {                                                                                    \
        const int kk_ = (u) >> 2, cu_ = (u) & 3;                                         \
        char* dst_ = smem + SMEM_B + ((u) & 3) * 16384 + w * 2048;                       \
        _Pragma("unroll")                                                                \
        for (int i = 0; i < 2; ++i) {                                                    \
            const int e = w * 128 + i * 64 + lane;                                       \
            const int c = e >> 2, s = e & 3;                                             \
            const char* src = pbB + ((size_t)(cu_ * 256 + c) << 9) + (kk_ << 6)          \
                                  + ((s ^ (c & 3)) << 4);                                \
            gload_lds16(src, dst_ + i * 1024);                                           \
        }                                                                                \
    }

    // prologue: issue units 0..2, then cooperative A-stage (32 rows x 256 dims)
    STAGE(0);
    STAGE(1);
    STAGE(2);
    float rinvLocal = 0.f;
    {
        const int row = tid >> 4;            // 0..31
        const int seg = tid & 15;            // 16 dims (64 B) each
        const float* qrow = qf + (qbase + row) * (size_t)DD + seg * 16;
        float4 f0 = *reinterpret_cast<const float4*>(qrow + 0);
        float4 f1 = *reinterpret_cast<const float4*>(qrow + 4);
        float4 f2 = *reinterpret_cast<const float4*>(qrow + 8);
        float4 f3 = *reinterpret_cast<const float4*>(qrow + 12);
        float ss = f0.x*f0.x + f0.y*f0.y + f0.z*f0.z + f0.w*f0.w
                 + f1.x*f1.x + f1.y*f1.y + f1.z*f1.z + f1.w*f1.w
                 + f2.x*f2.x + f2.y*f2.y + f2.z*f2.z + f2.w*f2.w
                 + f3.x*f3.x + f3.y*f3.y + f3.z*f3.z + f3.w*f3.w;
        ss += __shfl_xor(ss, 1); ss += __shfl_xor(ss, 2);
        ss += __shfl_xor(ss, 4); ss += __shfl_xor(ss, 8);
        rinvLocal = 1.0f / fmaxf(sqrtf(ss), 1e-8f);
        short8 h0, h1;
        h0[0]=(short)f2bf(f0.x); h0[1]=(short)f2bf(f0.y); h0[2]=(short)f2bf(f0.z); h0[3]=(short)f2bf(f0.w);
        h0[4]=(short)f2bf(f1.x); h0[5]=(short)f2bf(f1.y); h0[6]=(short)f2bf(f1.z); h0[7]=(short)f2bf(f1.w);
        h1[0]=(short)f2bf(f2.x); h1[1]=(short)f2bf(f2.y); h1[2]=(short)f2bf(f2.z); h1[3]=(short)f2bf(f2.w);
        h1[4]=(short)f2bf(f3.x); h1[5]=(short)f2bf(f3.y); h1[6]=(short)f2bf(f3.z); h1[7]=(short)f2bf(f3.w);
        const int x = row & 7;
        char* aRow = smem + SMEM_A + row * 512;
        *reinterpret_cast<short8*>(aRow + (((seg*2)     ^ x) << 4)) = h0;
        *reinterpret_cast<short8*>(aRow + (((seg*2 + 1) ^ x) << 4)) = h1;
    }
    __syncthreads();   // full drain: units 0-2 + A all in LDS (prologue only)

    // hoist query frags: a[kk] = q[qg*16+r16][kk*32 + g*8 ..+8]; 32 VGPRs
    short8 a[8];
    {
        const int row = qg * 16 + r16;
#pragma unroll
        for (int kk = 0; kk < 8; ++kk) {
            const int chunk = (kk * 4 + g) ^ (row & 7);
            a[kk] = *reinterpret_cast<const short8*>(smem + SMEM_A + row * 512 + chunk * 16);
        }
    }
    __syncthreads();   // all waves hoisted; A region free for overlays

    if ((lane & 15) == 0)
        reinterpret_cast<float*>(smem + SMEM_A)[tid >> 4] = rinvLocal;

    f32x4 acc[16];
#pragma unroll
    for (int n = 0; n < 16; ++n) acc[n] = (f32x4){0.f, 0.f, 0.f, 0.f};

    // ---- main loop: 32 units, ring-4, stage-after-barrier, counted vmcnt ----
#pragma unroll
    for (int u = 0; u < 32; ++u) {
        if (u <= 29)      { asm volatile("s_waitcnt vmcnt(4)" ::: "memory"); }
        else if (u == 30) { asm volatile("s_waitcnt vmcnt(2)" ::: "memory"); }
        else              { asm volatile("s_waitcnt vmcnt(0)" ::: "memory"); }
        asm volatile("s_barrier" ::: "memory");
        if (u + 3 < 32) STAGE(u + 3);
        const int kk = u >> 2, cu = u & 3;
        const char* base = smem + SMEM_B + (u & 3) * 16384;
        __builtin_amdgcn_s_setprio(1);
#pragma unroll
        for (int np = 0; np < 4; ++np) {
            const int cl = np * 64 + cq * 16 + r16;          // class within unit
            short8 b = *reinterpret_cast<const short8*>(base + cl * 64 + ((g ^ (cl & 3)) << 4));
            acc[cu * 4 + np] = __builtin_amdgcn_mfma_f32_16x16x32_bf16(b, a[kk], acc[cu * 4 + np], 0, 0, 0);
        }
        __builtin_amdgcn_s_setprio(0);
    }
    asm volatile("s_waitcnt lgkmcnt(0)" ::: "memory");
    asm volatile("s_barrier" ::: "memory");   // K done; B ring becomes image

    // ---- epilogue: qinv scale + row log_softmax (raw lgkm barriers only) ----
    float* qinvLds = reinterpret_cast<float*>(smem + SMEM_A);
    float* redM = reinterpret_cast<float*>(smem + SMEM_A + 1024);   // [32][4]
    float* redS = reinterpret_cast<float*>(smem + SMEM_A + 2048);   // [32][4]
    const int myrow = qg * 16 + r16;
    const float qi = qinvLds[myrow];

#pragma unroll
    for (int n = 0; n < 16; ++n)
#pragma unroll
        for (int j = 0; j < 4; ++j) acc[n][j] *= qi;

    float m = acc[0][0];
#pragma unroll
    for (int n = 0; n < 16; ++n)
#pragma unroll
        for (int j = 0; j < 4; ++j) m = fmaxf(m, acc[n][j]);
    m = fmaxf(m, __shfl_xor(m, 16));
    m = fmaxf(m, __shfl_xor(m, 32));
    if (lane < 16) redM[myrow * 4 + cq] = m;
    asm volatile("s_waitcnt lgkmcnt(0)" ::: "memory");
    asm volatile("s_barrier" ::: "memory");
    float rowM = redM[myrow * 4 + 0];
#pragma unroll
    for (int k = 1; k < 4; ++k) rowM = fmaxf(rowM, redM[myrow * 4 + k]);

    float s = 0.f;
#pragma unroll
    for (int n = 0; n < 16; ++n)
#pragma unroll
        for (int j = 0; j < 4; ++j) s += __expf(acc[n][j] - rowM);
    s += __shfl_xor(s, 16);
    s += __shfl_xor(s, 32);
    if (lane < 16) redS[myrow * 4 + cq] = s;
    asm volatile("s_waitcnt lgkmcnt(0)" ::: "memory");
    asm volatile("s_barrier" ::: "memory");
    float rs = redS[myrow * 4 + 0];
#pragma unroll
    for (int k = 1; k < 4; ++k) rs += redS[myrow * 4 + k];
    const float lse = rowM + __logf(rs);

    // ---- stores via [16][1024] f32 image in dead B ring, 2 passes.
    // Raw lgkm barriers: global stores drain outside the critical path.
#pragma unroll
    for (int pass = 0; pass < 2; ++pass) {
        if (qg == pass) {
#pragma unroll
            for (int n = 0; n < 16; ++n) {
                f32x4 v;
#pragma unroll
                for (int j = 0; j < 4; ++j) v[j] = acc[n][j] - lse;
                const int slot = n * 16 + cq * 4 + g;           // 16B slot in row
                *reinterpret_cast<f32x4*>(smem + r16 * 4096 + ((slot ^ (r16 & 7)) << 4)) = v;
            }
        }
        asm volatile("s_waitcnt lgkmcnt(0)" ::: "memory");
        asm volatile("s_barrier" ::: "memory");
        {
            const int orow = tid >> 5;        // 0..15
            const int s0  = tid & 31;
            float* gout = out + (qbase + pass * 16 + orow) * (size_t)NC;
#pragma unroll
            for (int p = 0; p < 8; ++p) {
                const int slot = p * 32 + s0;
                f32x4 v = *reinterpret_cast<const f32x4*>(smem + orow * 4096 + ((slot ^ (orow & 7)) << 4));
                *reinterpret_cast<f32x4*>(gout + slot * 4) = v;
            }
        }
        asm volatile("s_waitcnt lgkmcnt(0)" ::: "memory");
        asm volatile("s_barrier" ::: "memory");   // image reads done
    }
}

extern "C" void kernel_launch(void* const* d_in, const int* in_sizes, int n_in,
                              void* d_out, int out_size, void* d_ws, size_t ws_size,
                              hipStream_t stream) {
    const float* sf     = (const float*)d_in[0];
    const int*   labels = (const int*)d_in[1];
    const float* qf     = (const float*)d_in[2];
    float* out = (float*)d_out;

    char* ws = (char*)d_ws;
    float* rinv         = (float*)ws;                          // 256 KiB
    unsigned short* pb  = (unsigned short*)(ws + 262144);      // 512 KiB
    int* cnts           = (int*)(ws + 786432);                 // 4 KiB
    int* lists          = (int*)(ws + 790528);                 // 512 KiB

    hipFuncSetAttribute(reinterpret_cast<const void*>(k_gemm_lsm),
                        hipFuncAttributeMaxDynamicSharedMemorySize, SMEM_TOTAL);

    hipMemsetAsync(cnts, 0, NC * sizeof(int), stream);

    k_count<<<NS / 4, 256, 0, stream>>>(sf, labels, rinv, cnts, lists);

    float* outTail = out + (size_t)out_size - NC;
    k_proto<<<NC, 256, 0, stream>>>(sf, rinv, cnts, lists, pb, outTail);

    k_gemm_lsm<<<NQ / BM, 512, SMEM_TOTAL, stream>>>(qf, pb, out);
}